// Round 6
// baseline (937.087 us; speedup 1.0000x reference)
//
#include <hip/hip_runtime.h>
#include <hip/hip_bf16.h>
#include <hip/hip_cooperative_groups.h>

namespace cg = cooperative_groups;

#define NDIM 256
#define NROT 32640          // C(256,2)
#define MATE (NDIM * NDIM)  // elements per plane
#define NODEE (2 * MATE)    // node = hi plane + lo plane (bf16 each)

typedef __bf16 bf16x4_t __attribute__((ext_vector_type(4)));
typedef __bf16 bf16x8_t __attribute__((ext_vector_type(8)));
typedef float f32x4_t __attribute__((ext_vector_type(4)));

// ---------------------------------------------------------------------------
// K1: build nseg segment products (seglen rotations each) applied to I, fp32
// in LDS; sincos fused. Output: bf16 hi/lo planes.
//   even seg -> TRANSPOSED ([c][k]); odd seg -> plain ([r][k]).
// nseg=128 -> 512 blocks at 69.7 KB LDS = 2 blocks/CU: half the chain length
// AND two waves/CU hiding each other's latency (R5: 1 wave/CU, 43.8 us).
// ---------------------------------------------------------------------------
__global__ __launch_bounds__(64, 1) void k_build(const float* __restrict__ rots,
                                                 __bf16* __restrict__ leaves,
                                                 int seglen) {
    __shared__ float tile[NDIM * 64];   // 64 KiB: 256 rows x 64 cols
    __shared__ float2 csl[510 + 8];
    const int t = threadIdx.x;          // 0..63
    const int seg = blockIdx.x >> 2;
    const int cgi = blockIdx.x & 3;
    const int col = cgi * 64 + t;

    const int kg0 = seg * seglen;
    for (int u = t; u < seglen; u += 64) {
        float th = rots[kg0 + u];
        float s, c;
        sincosf(th, &s, &c);
        csl[u] = make_float2(c, s);
    }
    for (int u = seglen + t; u < seglen + 8; u += 64) csl[u] = make_float2(1.f, 0.f);

    for (int r = 0; r < NDIM; r++) tile[r * 64 + t] = (r == col) ? 1.0f : 0.0f;
    // single wave: LDS ops execute in order, no barrier needed

    int k = 0;
    int i = 0, cum = 0;
    while (cum + (NDIM - 1 - i) <= kg0) { cum += NDIM - 1 - i; i++; }
    int j = i + 1 + (kg0 - cum);

    while (k < seglen) {
        float ri = tile[i * 64 + t];
        const int len = min(NDIM - j, seglen - k);
        const int jend = j + len;
        const int nb = len >> 3;

        if (nb > 0) {
            float2 cv[8]; float rj[8];
            #pragma unroll
            for (int u = 0; u < 8; u++) cv[u] = csl[k + u];
            #pragma unroll
            for (int u = 0; u < 8; u++) rj[u] = tile[(j + u) * 64 + t];
            for (int b = 0; b < nb - 1; b++) {
                float2 cvn[8]; float rjn[8];
                #pragma unroll
                for (int u = 0; u < 8; u++) cvn[u] = csl[k + 8 + u];
                #pragma unroll
                for (int u = 0; u < 8; u++) rjn[u] = tile[(j + 8 + u) * 64 + t];
                #pragma unroll
                for (int u = 0; u < 8; u++) {
                    float nri = fmaf(cv[u].x, ri, -(cv[u].y * rj[u]));
                    rj[u]     = fmaf(cv[u].y, ri,  cv[u].x * rj[u]);
                    ri = nri;
                }
                #pragma unroll
                for (int u = 0; u < 8; u++) tile[(j + u) * 64 + t] = rj[u];
                #pragma unroll
                for (int u = 0; u < 8; u++) { cv[u] = cvn[u]; rj[u] = rjn[u]; }
                j += 8; k += 8;
            }
            #pragma unroll
            for (int u = 0; u < 8; u++) {
                float nri = fmaf(cv[u].x, ri, -(cv[u].y * rj[u]));
                rj[u]     = fmaf(cv[u].y, ri,  cv[u].x * rj[u]);
                ri = nri;
            }
            #pragma unroll
            for (int u = 0; u < 8; u++) tile[(j + u) * 64 + t] = rj[u];
            j += 8; k += 8;
        }
        for (; j < jend; j++, k++) {
            float2 cv = csl[k];
            float rj = tile[j * 64 + t];
            float nri = fmaf(cv.x, ri, -(cv.y * rj));
            tile[j * 64 + t] = fmaf(cv.y, ri, cv.x * rj);
            ri = nri;
        }
        tile[i * 64 + t] = ri;
        if (j == NDIM) { i++; j = i + 1; }
    }

    __bf16* hi = leaves + (size_t)seg * NODEE;
    __bf16* lo = hi + MATE;
    if (seg & 1) {
        for (int r = 0; r < NDIM; r++) {
            float v = tile[r * 64 + t];
            __bf16 h = (__bf16)v;
            hi[r * NDIM + col] = h;
            lo[r * NDIM + col] = (__bf16)(v - (float)h);
        }
    } else {
        for (int r0 = 0; r0 < NDIM; r0 += 8) {
            bf16x8_t vh, vl;
            #pragma unroll
            for (int u = 0; u < 8; u++) {
                float v = tile[(r0 + u) * 64 + t];
                __bf16 h = (__bf16)v;
                vh[u] = h;
                vl[u] = (__bf16)(v - (float)h);
            }
            *(bf16x8_t*)&hi[(size_t)col * NDIM + r0] = vh;
            *(bf16x8_t*)&lo[(size_t)col * NDIM + r0] = vl;
        }
    }
}

// ---------------------------------------------------------------------------
// K2: ENTIRE combine tree in one cooperative kernel; grid.sync() between
// levels (replaces 6-7 dependent dispatches at ~20us each).
// node[p] = child[2p+1] @ child[2p]; children bf16 hi/lo; child[2p]
// transposed ([c][k]), child[2p+1] plain ([r][k]); C ~= Bh@Ah + Bh@Al + Bl@Ah.
// Per tile: 64x64 output, BK=128 (2 k-chunks), LDS 69.6 KB -> 2 blocks/CU,
// grid 512 = exactly co-resident. Levels read (lvl&1?B1:B0), write the other.
// ---------------------------------------------------------------------------
#define LDK2 136   // padded LDS row (bf16): 128 + 8; rows 2-way bank alias (free)
__global__ __launch_bounds__(256, 2) void k_tree(__bf16* __restrict__ B0,
                                                 __bf16* __restrict__ B1,
                                                 int nseg) {
    cg::grid_group grid = cg::this_grid();
    __shared__ __bf16 planes[4][64 * LDK2];   // Bhi, Blo, Ahi, Alo

    const int t = threadIdx.x;
    const int wid = t >> 6, lane = t & 63;
    const int wr2 = (wid >> 1) * 32, wc2 = (wid & 1) * 32;
    const int lrow = lane & 15, kg = lane >> 4;

    int nlev = 0;
    while ((1 << (nlev + 1)) <= nseg) nlev++;   // nseg = 2^nlev

    for (int lvl = 0; lvl < nlev; lvl++) {
        __bf16* src = (lvl & 1) ? B1 : B0;
        __bf16* dst = (lvl & 1) ? B0 : B1;
        const int npairs = nseg >> (lvl + 1);
        const bool finalLevel = (lvl == nlev - 1);

        for (int w = blockIdx.x; w < npairs * 16; w += gridDim.x) {
            const int p = w >> 4;
            const int qd = w & 15;
            const int rbq = (qd >> 2) * 64;   // output rows (B rows)
            const int cbq = (qd & 3) * 64;    // output cols (A rows, transposed)
            const __bf16* A = src + (size_t)(2 * p) * NODEE;       // transposed child
            const __bf16* Bm = src + (size_t)(2 * p + 1) * NODEE;  // plain child
            __bf16* Chi = dst + (size_t)p * NODEE;
            __bf16* Clo = Chi + MATE;
            const bool storeT = (!finalLevel) && ((p & 1) == 0);

            f32x4_t acc[2][2] = {};
            for (int kc = 0; kc < 256; kc += 128) {
                // stage 4 planes x 64 rows x 128 cols (16 B chunks, 4/thread/plane)
                const __bf16* sp[4] = {Bm, Bm + MATE, A, A + MATE};
                const int r0p[4] = {rbq, rbq, cbq, cbq};
                #pragma unroll
                for (int pl = 0; pl < 4; pl++) {
                    #pragma unroll
                    for (int q = 0; q < 4; q++) {
                        int c = q * 256 + t;
                        int row = c >> 4, sg = c & 15;
                        *(bf16x8_t*)&planes[pl][row * LDK2 + sg * 8] =
                            *(const bf16x8_t*)&sp[pl][(size_t)(r0p[pl] + row) * NDIM + kc + sg * 8];
                    }
                }
                __syncthreads();

                #pragma unroll
                for (int ks = 0; ks < 4; ks++) {
                    bf16x8_t afh[2], afl[2], bfh[2], bfl[2];
                    #pragma unroll
                    for (int mt = 0; mt < 2; mt++) {
                        int r = (wr2 + mt * 16 + lrow) * LDK2 + ks * 32 + kg * 8;
                        afh[mt] = *(const bf16x8_t*)&planes[0][r];
                        afl[mt] = *(const bf16x8_t*)&planes[1][r];
                    }
                    #pragma unroll
                    for (int nt = 0; nt < 2; nt++) {
                        int r = (wc2 + nt * 16 + lrow) * LDK2 + ks * 32 + kg * 8;
                        bfh[nt] = *(const bf16x8_t*)&planes[2][r];
                        bfl[nt] = *(const bf16x8_t*)&planes[3][r];
                    }
                    #pragma unroll
                    for (int mt = 0; mt < 2; mt++)
                        #pragma unroll
                        for (int nt = 0; nt < 2; nt++) {
                            acc[mt][nt] = __builtin_amdgcn_mfma_f32_16x16x32_bf16(afh[mt], bfh[nt], acc[mt][nt], 0, 0, 0);
                            acc[mt][nt] = __builtin_amdgcn_mfma_f32_16x16x32_bf16(afh[mt], bfl[nt], acc[mt][nt], 0, 0, 0);
                            acc[mt][nt] = __builtin_amdgcn_mfma_f32_16x16x32_bf16(afl[mt], bfh[nt], acc[mt][nt], 0, 0, 0);
                        }
                }
                __syncthreads();
            }

            // C/D: col = lane&15, row = (lane>>4)*4 + reg
            #pragma unroll
            for (int mt = 0; mt < 2; mt++)
                #pragma unroll
                for (int nt = 0; nt < 2; nt++) {
                    int grow = rbq + wr2 + mt * 16 + kg * 4;
                    int gcol = cbq + wc2 + nt * 16 + lrow;
                    if (storeT) {
                        bf16x4_t vh, vl;
                        #pragma unroll
                        for (int r = 0; r < 4; r++) {
                            float v = acc[mt][nt][r];
                            __bf16 h = (__bf16)v;
                            vh[r] = h;
                            vl[r] = (__bf16)(v - (float)h);
                        }
                        *(bf16x4_t*)&Chi[(size_t)gcol * NDIM + grow] = vh;
                        *(bf16x4_t*)&Clo[(size_t)gcol * NDIM + grow] = vl;
                    } else {
                        #pragma unroll
                        for (int r = 0; r < 4; r++) {
                            float v = acc[mt][nt][r];
                            __bf16 h = (__bf16)v;
                            Chi[(size_t)(grow + r) * NDIM + gcol] = h;
                            Clo[(size_t)(grow + r) * NDIM + gcol] = (__bf16)(v - (float)h);
                        }
                    }
                }
        }
        __threadfence();   // make this level's stores device-visible
        grid.sync();
    }
}

// ---------------------------------------------------------------------------
// K3: Y[b][c] = sum_k X[b][k] * Mhi[c][k]; Mhi bf16 row-major (root hi plane).
// BM=BN=128, BK=64 (4 iters), register prefetch of iter+1 global loads,
// 4 waves 2x2 of 64x64, LDS 36 KB.  (unchanged from R5: 43.6 us)
// ---------------------------------------------------------------------------
#define LDA 72    // padded LDS row (bf16), 144 B
__global__ __launch_bounds__(256, 2) void k_gemm(const float* __restrict__ X,
                                                 const __bf16* __restrict__ Mhi,
                                                 float* __restrict__ Y) {
    __shared__ __bf16 As[128 * LDA];
    __shared__ __bf16 Bs[128 * LDA];
    const int bx = blockIdx.x;
    const int xcd = bx & 7;
    const int q = bx >> 3;
    const int bn = (q & 1) * 128;
    const int bm = (xcd + (q >> 1) * 8) * 128;
    const int t = threadIdx.x;
    const int wid = t >> 6;
    const int lane = t & 63;
    const int wr = (wid >> 1) * 64;
    const int wc = (wid & 1) * 64;
    const int lrow = lane & 15;
    const int kg = lane >> 4;

    f32x4_t acc[4][4] = {};

    f32x4_t ra[8];
    bf16x8_t rb[4];

    #pragma unroll
    for (int qq = 0; qq < 8; qq++) {
        int g = qq * 256 + t;
        ra[qq] = *(const f32x4_t*)&X[(size_t)(bm + (g >> 4)) * 256 + (g & 15) * 4];
    }
    #pragma unroll
    for (int qq = 0; qq < 4; qq++) {
        int g = qq * 256 + t;
        rb[qq] = *(const bf16x8_t*)&Mhi[(size_t)(bn + (g >> 3)) * 256 + (g & 7) * 8];
    }

    #pragma unroll
    for (int it = 0; it < 4; it++) {
        #pragma unroll
        for (int qq = 0; qq < 8; qq++) {
            int g = qq * 256 + t;
            f32x4_t v = ra[qq];
            bf16x4_t h = {(__bf16)v.x, (__bf16)v.y, (__bf16)v.z, (__bf16)v.w};
            *(bf16x4_t*)&As[(g >> 4) * LDA + (g & 15) * 4] = h;
        }
        #pragma unroll
        for (int qq = 0; qq < 4; qq++) {
            int g = qq * 256 + t;
            *(bf16x8_t*)&Bs[(g >> 3) * LDA + (g & 7) * 8] = rb[qq];
        }
        __syncthreads();

        if (it < 3) {
            int kc = (it + 1) * 64;
            #pragma unroll
            for (int qq = 0; qq < 8; qq++) {
                int g = qq * 256 + t;
                ra[qq] = *(const f32x4_t*)&X[(size_t)(bm + (g >> 4)) * 256 + kc + (g & 15) * 4];
            }
            #pragma unroll
            for (int qq = 0; qq < 4; qq++) {
                int g = qq * 256 + t;
                rb[qq] = *(const bf16x8_t*)&Mhi[(size_t)(bn + (g >> 3)) * 256 + kc + (g & 7) * 8];
            }
        }

        #pragma unroll
        for (int k2 = 0; k2 < 2; k2++) {
            bf16x8_t af[4], bfr[4];
            #pragma unroll
            for (int mt = 0; mt < 4; mt++)
                af[mt] = *(const bf16x8_t*)&As[(wr + mt * 16 + lrow) * LDA + k2 * 32 + kg * 8];
            #pragma unroll
            for (int nt = 0; nt < 4; nt++)
                bfr[nt] = *(const bf16x8_t*)&Bs[(wc + nt * 16 + lrow) * LDA + k2 * 32 + kg * 8];
            #pragma unroll
            for (int mt = 0; mt < 4; mt++)
                #pragma unroll
                for (int nt = 0; nt < 4; nt++)
                    acc[mt][nt] = __builtin_amdgcn_mfma_f32_16x16x32_bf16(af[mt], bfr[nt], acc[mt][nt], 0, 0, 0);
        }
        __syncthreads();
    }

    const int ocol = bn + wc + lrow;
    const int orow = bm + wr + kg * 4;
    #pragma unroll
    for (int mt = 0; mt < 4; mt++)
        #pragma unroll
        for (int nt = 0; nt < 4; nt++)
            #pragma unroll
            for (int r = 0; r < 4; r++)
                Y[(size_t)(orow + mt * 16 + r) * 256 + ocol + nt * 16] = acc[mt][nt][r];
}

// ---------------------------------------------------------------------------
// workspace: B0 = nseg nodes, B1 = nseg/2 nodes (256 KB/node).
//   nseg=128: 32 MB + 16 MB = 48 MB (requires ws >= 48 MB; else nseg=64: 24 MB)
// levels alternate B0->B1->B0...; root in B1 if nlev odd else B0.
// ---------------------------------------------------------------------------
extern "C" void kernel_launch(void* const* d_in, const int* in_sizes, int n_in,
                              void* d_out, int out_size, void* d_ws, size_t ws_size,
                              hipStream_t stream) {
    const float* x = (const float*)d_in[0];
    const float* rots = (const float*)d_in[1];
    float* out = (float*)d_out;

    const size_t need128 = (size_t)(128 + 64) * NODEE * sizeof(__bf16);  // 48 MB
    int nseg, seglen, nlev;
    if (ws_size >= need128) { nseg = 128; seglen = 255; nlev = 7; }
    else                    { nseg = 64;  seglen = 510; nlev = 6; }

    __bf16* B0 = (__bf16*)d_ws;
    __bf16* B1 = B0 + (size_t)nseg * NODEE;
    __bf16* root = (nlev & 1) ? B1 : B0;

    k_build<<<nseg * 4, 64, 0, stream>>>(rots, B0, seglen);

    void* args[] = {(void*)&B0, (void*)&B1, (void*)&nseg};
    hipLaunchCooperativeKernel((const void*)k_tree, dim3(512), dim3(256), args, 0, stream);

    k_gemm<<<1024, 256, 0, stream>>>(x, root, out);
}